// Round 1
// 237.461 us; speedup vs baseline: 1.1212x; 1.1212x over previous
//
#include <hip/hip_runtime.h>

#define N_NODES 100000
#define N_EDGES 1200000
#define D 64

#define BSHIFT 10
#define NB ((N_NODES + 1023) >> BSHIFT)        // 98 buckets of 1024 nodes
#define EPB 2048                                // edges per partition block
#define P1_BLOCKS ((N_EDGES + EPB - 1) / EPB)   // 586
#define P2_CAP 16384                            // per-bucket edge capacity

typedef short bf16x8 __attribute__((ext_vector_type(8)));
typedef float f32x4 __attribute__((ext_vector_type(4)));
typedef unsigned short u16x4 __attribute__((ext_vector_type(4)));
typedef unsigned short u16x8 __attribute__((ext_vector_type(8)));

__device__ __forceinline__ short f2bf(float x) {
  unsigned u = __float_as_uint(x);
  unsigned r = (u + 0x7FFFu + ((u >> 16) & 1u)) >> 16;  // RNE
  return (short)r;
}
__device__ __forceinline__ float bf2f(short b) {
  return __uint_as_float(((unsigned)(unsigned short)b) << 16);
}

// ---------------- f32 -> bf16 bulk convert (for gather-side copies) ----------
__global__ __launch_bounds__(256) void cvt_bf(const float* __restrict__ in,
                                              unsigned short* __restrict__ o,
                                              int n8) {
  int i = blockIdx.x * 256 + threadIdx.x;
  if (i >= n8) return;
  const float4 a0 = *(const float4*)(in + (size_t)i * 8);
  const float4 a1 = *(const float4*)(in + (size_t)i * 8 + 4);
  const float f[8] = {a0.x, a0.y, a0.z, a0.w, a1.x, a1.y, a1.z, a1.w};
  u16x8 v;
#pragma unroll
  for (int j = 0; j < 8; ++j) v[j] = (unsigned short)f2bf(f[j]);
  *(u16x8*)(o + (size_t)i * 8) = v;
}

// ---------------- Phase 1a: per-bucket edge counts ---------------------------
__global__ __launch_bounds__(256) void p1_count(const int* __restrict__ row,
                                                int* __restrict__ bucketCount) {
  __shared__ int h[NB];
  const int t = threadIdx.x;
  for (int i = t; i < NB; i += 256) h[i] = 0;
  __syncthreads();
  const int base = blockIdx.x * EPB;
#pragma unroll
  for (int i = 0; i < EPB / 256; ++i) {
    int e = base + i * 256 + t;
    if (e < N_EDGES) atomicAdd(&h[row[e] >> BSHIFT], 1);
  }
  __syncthreads();
  for (int i = t; i < NB; i += 256)
    if (h[i]) atomicAdd(&bucketCount[i], h[i]);
}

// ---------------- Phase 1b: scan bucket counts -> starts + cursors ----------
__global__ __launch_bounds__(128) void p1_scan(const int* __restrict__ bucketCount,
                                               int* __restrict__ bucketStart,
                                               int* __restrict__ cursor) {
  __shared__ int lds[128];
  const int t = threadIdx.x;
  int v = (t < NB) ? bucketCount[t] : 0;
  lds[t] = v;
  __syncthreads();
  for (int off = 1; off < 128; off <<= 1) {
    int add = (t >= off) ? lds[t - off] : 0;
    __syncthreads();
    lds[t] += add;
    __syncthreads();
  }
  if (t < NB) {
    int start = lds[t] - v;
    bucketStart[t] = start;
    cursor[t] = start;
  }
  if (t == NB - 1) bucketStart[NB] = lds[t];
}

// ---------------- Phase 1c: partition (row,col) pairs into buckets -----------
__global__ __launch_bounds__(256) void p1_scatter(
    const int* __restrict__ row, const int* __restrict__ col,
    int* __restrict__ cursor, unsigned long long* __restrict__ pairBuf) {
  __shared__ int h[NB];
  __shared__ int hexcl[NB];
  __shared__ int gbase[NB];
  __shared__ int scan_lds[128];
  __shared__ unsigned long long staged[EPB];
  const int t = threadIdx.x;
  for (int i = t; i < NB; i += 256) h[i] = 0;
  __syncthreads();
  const int base = blockIdx.x * EPB;
  const int cnt = min(EPB, N_EDGES - base);

  int myrank[EPB / 256];
  int mybkt[EPB / 256];
  unsigned long long mypair[EPB / 256];
#pragma unroll
  for (int i = 0; i < EPB / 256; ++i) {
    int e = base + i * 256 + t;
    if (e < N_EDGES) {
      unsigned r = (unsigned)row[e];
      unsigned c = (unsigned)col[e];
      int b = (int)(r >> BSHIFT);
      mybkt[i] = b;
      mypair[i] = ((unsigned long long)r << 32) | c;
      myrank[i] = atomicAdd(&h[b], 1);
    } else {
      mybkt[i] = -1;
    }
  }
  __syncthreads();
  int v = 0;
  if (t < 128) { v = (t < NB) ? h[t] : 0; scan_lds[t] = v; }
  __syncthreads();
  for (int off = 1; off < 128; off <<= 1) {
    int add = (t >= off && t < 128) ? scan_lds[t - off] : 0;
    __syncthreads();
    if (t < 128) scan_lds[t] += add;
    __syncthreads();
  }
  if (t < NB) {
    hexcl[t] = scan_lds[t] - v;
    gbase[t] = (h[t] > 0) ? atomicAdd(&cursor[t], h[t]) : 0;
  }
  __syncthreads();
#pragma unroll
  for (int i = 0; i < EPB / 256; ++i)
    if (mybkt[i] >= 0) staged[hexcl[mybkt[i]] + myrank[i]] = mypair[i];
  __syncthreads();
  for (int i = t; i < cnt; i += 256) {
    unsigned long long p = staged[i];
    int b = (int)(p >> (32 + BSHIFT));
    pairBuf[gbase[b] + (i - hexcl[b])] = p;
  }
}

// ---------------- Phase 2: per-bucket local CSR ------------------------------
__global__ __launch_bounds__(1024) void p2_csr(
    const unsigned long long* __restrict__ pairBuf,
    const int* __restrict__ bucketStart,
    int* __restrict__ ends, int* __restrict__ sortedCol) {
  __shared__ int hist[1024];
  __shared__ int sc[1024];
  __shared__ unsigned short rankLDS[P2_CAP];
  const int t = threadIdx.x;
  const int b = blockIdx.x;
  const int base = bucketStart[b];
  const int cnt = min(bucketStart[b + 1] - base, P2_CAP);
  hist[t] = 0;
  __syncthreads();
  for (int i = t; i < cnt; i += 1024) {
    int lr = (int)((pairBuf[base + i] >> 32) & ((1 << BSHIFT) - 1));
    rankLDS[i] = (unsigned short)atomicAdd(&hist[lr], 1);
  }
  __syncthreads();
  int v = hist[t];
  sc[t] = v;
  __syncthreads();
  for (int off = 1; off < 1024; off <<= 1) {
    int add = (t >= off) ? sc[t - off] : 0;
    __syncthreads();
    sc[t] += add;
    __syncthreads();
  }
  const int node = (b << BSHIFT) + t;
  if (node < N_NODES) ends[node] = base + sc[t];
  const int excl = sc[t] - v;
  __syncthreads();
  sc[t] = excl;
  __syncthreads();
  for (int i = t; i < cnt; i += 1024) {
    unsigned long long p = pairBuf[base + i];
    int lr = (int)((p >> 32) & ((1 << BSHIFT) - 1));
    sortedCol[base + sc[lr] + (int)rankLDS[i]] = (int)(unsigned)p;
  }
}

// ---------------- Mean aggregation: bf16 gathers, one wave per node ----------
// Gathers 128B bf16 rows (half the line traffic of f32). Merged fast/tail
// loop keeps 4 exec-masked loads in flight per wave (mean degree = 12).
// Output written as bf16 (consumed directly as MFMA A-hi; A-lo == 0 exactly).
__global__ __launch_bounds__(256) void sage_agg(
    const unsigned short* __restrict__ xb, const int* __restrict__ ends,
    const int* __restrict__ sortedCol, unsigned short* __restrict__ agg, int n) {
  const int lane = threadIdx.x & 63;
  const int g = lane >> 4;
  const int fq = lane & 15;
  const int gwave = (blockIdx.x * blockDim.x + threadIdx.x) >> 6;
  const int nwaves = (gridDim.x * blockDim.x) >> 6;

  for (int r = gwave; r < n; r += nwaves) {
    const int start = (r == 0) ? 0 : ends[r - 1];
    const int end = ends[r];
    const int deg = end - start;
    float4 acc = make_float4(0.f, 0.f, 0.f, 0.f);

    for (int base = start; base < end; base += 64) {
      const int m = min(64, end - base);
      const int cv = (lane < m) ? sortedCol[base + lane] : 0;
      for (int j = 0; j < m; j += 16) {
        const int i0 = j + 0 + g, i1 = j + 4 + g, i2 = j + 8 + g, i3 = j + 12 + g;
        const int c0 = __shfl(cv, i0 < m ? i0 : 0);
        const int c1 = __shfl(cv, i1 < m ? i1 : 0);
        const int c2 = __shfl(cv, i2 < m ? i2 : 0);
        const int c3 = __shfl(cv, i3 < m ? i3 : 0);
        u16x4 v0, v1, v2, v3;
        if (i0 < m) v0 = *(const u16x4*)(xb + (size_t)c0 * D + fq * 4);
        if (i1 < m) v1 = *(const u16x4*)(xb + (size_t)c1 * D + fq * 4);
        if (i2 < m) v2 = *(const u16x4*)(xb + (size_t)c2 * D + fq * 4);
        if (i3 < m) v3 = *(const u16x4*)(xb + (size_t)c3 * D + fq * 4);
        if (i0 < m) { acc.x += bf2f(v0[0]); acc.y += bf2f(v0[1]);
                      acc.z += bf2f(v0[2]); acc.w += bf2f(v0[3]); }
        if (i1 < m) { acc.x += bf2f(v1[0]); acc.y += bf2f(v1[1]);
                      acc.z += bf2f(v1[2]); acc.w += bf2f(v1[3]); }
        if (i2 < m) { acc.x += bf2f(v2[0]); acc.y += bf2f(v2[1]);
                      acc.z += bf2f(v2[2]); acc.w += bf2f(v2[3]); }
        if (i3 < m) { acc.x += bf2f(v3[0]); acc.y += bf2f(v3[1]);
                      acc.z += bf2f(v3[2]); acc.w += bf2f(v3[3]); }
      }
    }
    acc.x += __shfl_xor(acc.x, 16); acc.x += __shfl_xor(acc.x, 32);
    acc.y += __shfl_xor(acc.y, 16); acc.y += __shfl_xor(acc.y, 32);
    acc.z += __shfl_xor(acc.z, 16); acc.z += __shfl_xor(acc.z, 32);
    acc.w += __shfl_xor(acc.w, 16); acc.w += __shfl_xor(acc.w, 32);
    if (g == 0) {
      const float s = 1.0f / (float)max(deg, 1);
      u16x4 o;
      o[0] = (unsigned short)f2bf(acc.x * s);
      o[1] = (unsigned short)f2bf(acc.y * s);
      o[2] = (unsigned short)f2bf(acc.z * s);
      o[3] = (unsigned short)f2bf(acc.w * s);
      *(u16x4*)(agg + (size_t)r * D + fq * 4) = o;
    }
  }
}

// ---------------- W pre-swizzle: fp32 W[128][64] -> bf16 hi/lo fragments -----
__global__ __launch_bounds__(256) void w_swizzle(const float* __restrict__ W,
                                                 short* __restrict__ wh,
                                                 short* __restrict__ wl) {
  int i = blockIdx.x * blockDim.x + threadIdx.x;
  if (i >= 4 * 4 * 64 * 8) return;
  int j = i & 7;
  int l = (i >> 3) & 63;
  int s = (i >> 9) & 3;
  int t = i >> 11;
  int k = s * 32 + ((l >> 4) * 8) + j;
  int n = t * 16 + (l & 15);
  float v = W[k * 64 + n];
  short hb = f2bf(v);
  short lb = f2bf(v - bf2f(hb));
  wh[i] = hb;
  wl[i] = lb;
}

// ---------------- Concat-matmul via split-bf16 MFMA --------------------------
// C[100000,64] = concat(x,agg)[.,128] @ W[128,64] + b.
// Self half (s<2): f32 rows, hi/lo split -> 3 MFMAs. Agg half (s>=2): bf16
// rows read directly (lo == 0 exactly) -> 2 MFMAs. 40 MFMAs/tile.
// Layer 1 additionally emits a bf16 copy of h for the layer-2 gather.
__global__ __launch_bounds__(256) void sage_mm(
    const float* __restrict__ xin, const unsigned short* __restrict__ aggb,
    const short* __restrict__ wh, const short* __restrict__ wl,
    const float* __restrict__ b, float* __restrict__ out,
    unsigned short* __restrict__ hb, int doRelu) {
  const int lane = threadIdx.x & 63;
  const int m = lane & 15;
  const int q = lane >> 4;
  const int gwave = (blockIdx.x * blockDim.x + threadIdx.x) >> 6;
  const int nwaves = (gridDim.x * blockDim.x) >> 6;
  const int nTiles = N_NODES / 16;  // 6250

  for (int tile = gwave; tile < nTiles; tile += nwaves) {
    const int r0 = tile * 16;
    f32x4 acc[4];
#pragma unroll
    for (int t = 0; t < 4; ++t) {
      const float bv = b[t * 16 + m];
      acc[t][0] = bv; acc[t][1] = bv; acc[t][2] = bv; acc[t][3] = bv;
    }

#pragma unroll
    for (int s = 0; s < 4; ++s) {
      const int kb = (s & 1) * 32 + q * 8;  // offset within the 64-wide row
      bf16x8 Ah, Al;
      if (s < 2) {
        const float* rowp = xin + (size_t)(r0 + m) * D + kb;
        const float4 a0 = *(const float4*)rowp;
        const float4 a1 = *(const float4*)(rowp + 4);
        const float f[8] = {a0.x, a0.y, a0.z, a0.w, a1.x, a1.y, a1.z, a1.w};
#pragma unroll
        for (int j = 0; j < 8; ++j) {
          const short hv = f2bf(f[j]);
          Ah[j] = hv;
          Al[j] = f2bf(f[j] - bf2f(hv));
        }
      } else {
        Ah = *(const bf16x8*)(aggb + (size_t)(r0 + m) * D + kb);
      }
#pragma unroll
      for (int t = 0; t < 4; ++t) {
        const int bi = ((t * 4 + s) * 64 + lane) * 8;
        const bf16x8 Bh = *(const bf16x8*)(wh + bi);
        const bf16x8 Bl = *(const bf16x8*)(wl + bi);
        acc[t] = __builtin_amdgcn_mfma_f32_16x16x32_bf16(Ah, Bh, acc[t], 0, 0, 0);
        acc[t] = __builtin_amdgcn_mfma_f32_16x16x32_bf16(Ah, Bl, acc[t], 0, 0, 0);
        if (s < 2)
          acc[t] = __builtin_amdgcn_mfma_f32_16x16x32_bf16(Al, Bh, acc[t], 0, 0, 0);
      }
    }

    // C layout: col = t*16 + m, row = q*4 + rg
#pragma unroll
    for (int t = 0; t < 4; ++t) {
#pragma unroll
      for (int rg = 0; rg < 4; ++rg) {
        float v = acc[t][rg];
        if (doRelu) v = fmaxf(v, 0.0f);
        const size_t oi = (size_t)(r0 + q * 4 + rg) * D + t * 16 + m;
        out[oi] = v;
        if (doRelu) hb[oi] = (unsigned short)f2bf(v);
      }
    }
  }
}

extern "C" void kernel_launch(void* const* d_in, const int* in_sizes, int n_in,
                              void* d_out, int out_size, void* d_ws, size_t ws_size,
                              hipStream_t stream) {
  const float* x  = (const float*)d_in[0];
  const int*   ei = (const int*)d_in[1];
  const float* W1 = (const float*)d_in[2];
  const float* b1 = (const float*)d_in[3];
  const float* W2 = (const float*)d_in[4];
  const float* b2 = (const float*)d_in[5];
  float* out = (float*)d_out;

  const int* row = ei;            // edge_index[0]
  const int* col = ei + N_EDGES;  // edge_index[1]

  // ws layout:
  //   ends[N] | sortedCol[E] | bucket meta | w1h|w1l|w2h|w2l (4×16KB)
  //   | xh[N*64 bf16] | hb[N*64 bf16]
  //   | union{ pairBuf[E u64] (9.6MB), aggbf[N*64 bf16] (12.8MB) }
  char* ws = (char*)d_ws;
  int* endsArr = (int*)ws;
  size_t off = ((size_t)N_NODES * sizeof(int) + 4095) & ~(size_t)4095;
  int* sortedCol = (int*)(ws + off);
  off += ((size_t)N_EDGES * sizeof(int) + 4095) & ~(size_t)4095;
  int* bucketCount = (int*)(ws + off);
  int* bucketStart = bucketCount + 128;
  int* cursor = bucketStart + 256;
  off += 4096;
  short* w1h = (short*)(ws + off); off += 8192 * sizeof(short);
  short* w1l = (short*)(ws + off); off += 8192 * sizeof(short);
  short* w2h = (short*)(ws + off); off += 8192 * sizeof(short);
  short* w2l = (short*)(ws + off); off += 8192 * sizeof(short);
  unsigned short* xh = (unsigned short*)(ws + off);
  off += (size_t)N_NODES * D * sizeof(unsigned short);
  unsigned short* hb = (unsigned short*)(ws + off);
  off += (size_t)N_NODES * D * sizeof(unsigned short);
  off = (off + 4095) & ~(size_t)4095;
  unsigned long long* pairBuf = (unsigned long long*)(ws + off);
  unsigned short* aggbf = (unsigned short*)(ws + off);  // union: pairBuf dead
                                                        // before first sage_agg

  hipMemsetAsync(bucketCount, 0, NB * sizeof(int), stream);

  // ---- W pre-swizzle + x->bf16 (independent of CSR) ----
  w_swizzle<<<32, 256, 0, stream>>>(W1, w1h, w1l);
  w_swizzle<<<32, 256, 0, stream>>>(W2, w2h, w2l);
  cvt_bf<<<(N_NODES * D / 8 + 255) / 256, 256, 0, stream>>>(x, xh, N_NODES * D / 8);

  // ---- CSR build: bucketed two-phase partition ----
  p1_count<<<P1_BLOCKS, 256, 0, stream>>>(row, bucketCount);
  p1_scan<<<1, 128, 0, stream>>>(bucketCount, bucketStart, cursor);
  p1_scatter<<<P1_BLOCKS, 256, 0, stream>>>(row, col, cursor, pairBuf);
  p2_csr<<<NB, 1024, 0, stream>>>(pairBuf, bucketStart, endsArr, sortedCol);

  // ---- Layer 1: h = relu(concat(x, mean(x)) @ W1 + b1), h in d_out (+bf16 hb) ----
  sage_agg<<<2048, 256, 0, stream>>>(xh, endsArr, sortedCol, aggbf, N_NODES);
  sage_mm<<<1024, 256, 0, stream>>>(x, aggbf, w1h, w1l, b1, out, hb, 1);

  // ---- Layer 2: out = concat(h, mean(h)) @ W2 + b2 (in place over h) ----
  sage_agg<<<2048, 256, 0, stream>>>(hb, endsArr, sortedCol, aggbf, N_NODES);
  sage_mm<<<1024, 256, 0, stream>>>(out, aggbf, w2h, w2l, b2, out, hb, 0);
}

// Round 2
// 234.301 us; speedup vs baseline: 1.1363x; 1.0135x over previous
//
#include <hip/hip_runtime.h>

#define N_NODES 100000
#define N_EDGES 1200000
#define D 64

#define BSHIFT 8
#define NB ((N_NODES + 255) >> BSHIFT)          // 391 buckets of 256 nodes
#define EPB 2048                                 // edges per partition block
#define P1_BLOCKS ((N_EDGES + EPB - 1) / EPB)    // 586
#define P2_CAP 4096                              // per-bucket edge capacity
                                                 // (mean 3072, sigma~55 -> 18 sigma)

typedef short bf16x8 __attribute__((ext_vector_type(8)));
typedef float f32x4 __attribute__((ext_vector_type(4)));
typedef unsigned short u16x4 __attribute__((ext_vector_type(4)));
typedef unsigned short u16x8 __attribute__((ext_vector_type(8)));

__device__ __forceinline__ short f2bf(float x) {
  unsigned u = __float_as_uint(x);
  unsigned r = (u + 0x7FFFu + ((u >> 16) & 1u)) >> 16;  // RNE
  return (short)r;
}
__device__ __forceinline__ float bf2f(short b) {
  return __uint_as_float(((unsigned)(unsigned short)b) << 16);
}

// ---------------- Prep: W swizzle (both layers) + x -> bf16 hi/lo ------------
// blocks 0..31: W1 swizzle; 32..63: W2 swizzle; 64..: x split.
// W fragment layout (m89-verified): for n-tile t, k-step s, lane l:
// B[k = s*32 + (l>>4)*8 + j][n = t*16 + (l&15)], stored ((t*4+s)*64+l)*8+j.
__device__ __forceinline__ void w_swz(const float* __restrict__ W,
                                      short* __restrict__ wh,
                                      short* __restrict__ wl, int blk) {
  int i = blk * 256 + threadIdx.x;   // 0..8191
  int j = i & 7;
  int l = (i >> 3) & 63;
  int s = (i >> 9) & 3;
  int t = i >> 11;
  int k = s * 32 + ((l >> 4) * 8) + j;
  int n = t * 16 + (l & 15);
  float v = W[k * 64 + n];
  short hb = f2bf(v);
  wh[i] = hb;
  wl[i] = f2bf(v - bf2f(hb));
}

__global__ __launch_bounds__(256) void prep(
    const float* __restrict__ x, unsigned short* __restrict__ xh,
    unsigned short* __restrict__ xl,
    const float* __restrict__ W1, short* __restrict__ w1h, short* __restrict__ w1l,
    const float* __restrict__ W2, short* __restrict__ w2h, short* __restrict__ w2l) {
  const int bid = blockIdx.x;
  if (bid < 32) { w_swz(W1, w1h, w1l, bid); return; }
  if (bid < 64) { w_swz(W2, w2h, w2l, bid - 32); return; }
  int i = (bid - 64) * 256 + threadIdx.x;          // octet index
  if (i >= N_NODES * D / 8) return;
  const float4 a0 = *(const float4*)(x + (size_t)i * 8);
  const float4 a1 = *(const float4*)(x + (size_t)i * 8 + 4);
  const float f[8] = {a0.x, a0.y, a0.z, a0.w, a1.x, a1.y, a1.z, a1.w};
  u16x8 vh, vl;
#pragma unroll
  for (int j = 0; j < 8; ++j) {
    const short hb = f2bf(f[j]);
    vh[j] = (unsigned short)hb;
    vl[j] = (unsigned short)f2bf(f[j] - bf2f(hb));
  }
  *(u16x8*)(xh + (size_t)i * 8) = vh;
  *(u16x8*)(xl + (size_t)i * 8) = vl;
}

// ---------------- Phase 1a: per-bucket edge counts ---------------------------
__global__ __launch_bounds__(256) void p1_count(const int* __restrict__ row,
                                                int* __restrict__ bucketCount) {
  __shared__ int h[NB];
  const int t = threadIdx.x;
  for (int i = t; i < NB; i += 256) h[i] = 0;
  __syncthreads();
  const int base = blockIdx.x * EPB;
#pragma unroll
  for (int i = 0; i < EPB / 256; ++i) {
    int e = base + i * 256 + t;
    if (e < N_EDGES) atomicAdd(&h[row[e] >> BSHIFT], 1);
  }
  __syncthreads();
  for (int i = t; i < NB; i += 256)
    if (h[i]) atomicAdd(&bucketCount[i], h[i]);
}

// ---------------- Phase 1b: scan bucket counts -> starts + cursors ----------
__global__ __launch_bounds__(512) void p1_scan(const int* __restrict__ bucketCount,
                                               int* __restrict__ bucketStart,
                                               int* __restrict__ cursor) {
  __shared__ int lds[512];
  const int t = threadIdx.x;
  int v = (t < NB) ? bucketCount[t] : 0;
  lds[t] = v;
  __syncthreads();
  for (int off = 1; off < 512; off <<= 1) {
    int add = (t >= off) ? lds[t - off] : 0;
    __syncthreads();
    lds[t] += add;
    __syncthreads();
  }
  if (t < NB) {
    int start = lds[t] - v;
    bucketStart[t] = start;
    cursor[t] = start;
  }
  if (t == NB - 1) bucketStart[NB] = lds[t];
}

// ---------------- Phase 1c: partition (row,col) pairs into buckets -----------
__global__ __launch_bounds__(512) void p1_scatter(
    const int* __restrict__ row, const int* __restrict__ col,
    int* __restrict__ cursor, unsigned long long* __restrict__ pairBuf) {
  __shared__ int h[NB];
  __shared__ int hexcl[NB];
  __shared__ int gbase[NB];
  __shared__ int scan_lds[512];
  __shared__ unsigned long long staged[EPB];
  const int t = threadIdx.x;
  for (int i = t; i < NB; i += 512) h[i] = 0;
  __syncthreads();
  const int base = blockIdx.x * EPB;
  const int cnt = min(EPB, N_EDGES - base);

  int myrank[EPB / 512];
  int mybkt[EPB / 512];
  unsigned long long mypair[EPB / 512];
#pragma unroll
  for (int i = 0; i < EPB / 512; ++i) {
    int e = base + i * 512 + t;
    if (e < N_EDGES) {
      unsigned r = (unsigned)row[e];
      unsigned c = (unsigned)col[e];
      int b = (int)(r >> BSHIFT);
      mybkt[i] = b;
      mypair[i] = ((unsigned long long)r << 32) | c;
      myrank[i] = atomicAdd(&h[b], 1);
    } else {
      mybkt[i] = -1;
    }
  }
  __syncthreads();
  int v = (t < NB) ? h[t] : 0;
  scan_lds[t] = v;
  __syncthreads();
  for (int off = 1; off < 512; off <<= 1) {
    int add = (t >= off) ? scan_lds[t - off] : 0;
    __syncthreads();
    scan_lds[t] += add;
    __syncthreads();
  }
  if (t < NB) {
    hexcl[t] = scan_lds[t] - v;
    gbase[t] = (h[t] > 0) ? atomicAdd(&cursor[t], h[t]) : 0;
  }
  __syncthreads();
#pragma unroll
  for (int i = 0; i < EPB / 512; ++i)
    if (mybkt[i] >= 0) staged[hexcl[mybkt[i]] + myrank[i]] = mypair[i];
  __syncthreads();
  for (int i = t; i < cnt; i += 512) {
    unsigned long long p = staged[i];
    int b = (int)(p >> (32 + BSHIFT));
    pairBuf[gbase[b] + (i - hexcl[b])] = p;
  }
}

// ---------------- Phase 2: per-bucket local CSR ------------------------------
// 391 blocks of 256 threads (was 98 x 1024): full-machine occupancy, 8-step scan.
__global__ __launch_bounds__(256) void p2_csr(
    const unsigned long long* __restrict__ pairBuf,
    const int* __restrict__ bucketStart,
    int* __restrict__ ends, int* __restrict__ sortedCol) {
  __shared__ int hist[256];
  __shared__ int sc[256];
  __shared__ unsigned short rankLDS[P2_CAP];
  const int t = threadIdx.x;
  const int b = blockIdx.x;
  const int base = bucketStart[b];
  const int cnt = min(bucketStart[b + 1] - base, P2_CAP);
  hist[t] = 0;
  __syncthreads();
  for (int i = t; i < cnt; i += 256) {
    int lr = (int)((pairBuf[base + i] >> 32) & ((1 << BSHIFT) - 1));
    rankLDS[i] = (unsigned short)atomicAdd(&hist[lr], 1);
  }
  __syncthreads();
  int v = hist[t];
  sc[t] = v;
  __syncthreads();
  for (int off = 1; off < 256; off <<= 1) {
    int add = (t >= off) ? sc[t - off] : 0;
    __syncthreads();
    sc[t] += add;
    __syncthreads();
  }
  const int node = (b << BSHIFT) + t;
  if (node < N_NODES) ends[node] = base + sc[t];
  const int excl = sc[t] - v;
  __syncthreads();
  sc[t] = excl;
  __syncthreads();
  for (int i = t; i < cnt; i += 256) {
    unsigned long long p = pairBuf[base + i];
    int lr = (int)((p >> 32) & ((1 << BSHIFT) - 1));
    sortedCol[base + sc[lr] + (int)rankLDS[i]] = (int)(unsigned)p;
  }
}

// ---------------- Mean aggregation: bf16 gathers, one wave per node ----------
__global__ __launch_bounds__(256) void sage_agg(
    const unsigned short* __restrict__ xb, const int* __restrict__ ends,
    const int* __restrict__ sortedCol, unsigned short* __restrict__ agg, int n) {
  const int lane = threadIdx.x & 63;
  const int g = lane >> 4;
  const int fq = lane & 15;
  const int gwave = (blockIdx.x * blockDim.x + threadIdx.x) >> 6;
  const int nwaves = (gridDim.x * blockDim.x) >> 6;

  for (int r = gwave; r < n; r += nwaves) {
    const int start = (r == 0) ? 0 : ends[r - 1];
    const int end = ends[r];
    const int deg = end - start;
    float4 acc = make_float4(0.f, 0.f, 0.f, 0.f);

    for (int base = start; base < end; base += 64) {
      const int m = min(64, end - base);
      const int cv = (lane < m) ? sortedCol[base + lane] : 0;
      for (int j = 0; j < m; j += 16) {
        const int i0 = j + 0 + g, i1 = j + 4 + g, i2 = j + 8 + g, i3 = j + 12 + g;
        const int c0 = __shfl(cv, i0 < m ? i0 : 0);
        const int c1 = __shfl(cv, i1 < m ? i1 : 0);
        const int c2 = __shfl(cv, i2 < m ? i2 : 0);
        const int c3 = __shfl(cv, i3 < m ? i3 : 0);
        u16x4 v0, v1, v2, v3;
        if (i0 < m) v0 = *(const u16x4*)(xb + (size_t)c0 * D + fq * 4);
        if (i1 < m) v1 = *(const u16x4*)(xb + (size_t)c1 * D + fq * 4);
        if (i2 < m) v2 = *(const u16x4*)(xb + (size_t)c2 * D + fq * 4);
        if (i3 < m) v3 = *(const u16x4*)(xb + (size_t)c3 * D + fq * 4);
        if (i0 < m) { acc.x += bf2f(v0[0]); acc.y += bf2f(v0[1]);
                      acc.z += bf2f(v0[2]); acc.w += bf2f(v0[3]); }
        if (i1 < m) { acc.x += bf2f(v1[0]); acc.y += bf2f(v1[1]);
                      acc.z += bf2f(v1[2]); acc.w += bf2f(v1[3]); }
        if (i2 < m) { acc.x += bf2f(v2[0]); acc.y += bf2f(v2[1]);
                      acc.z += bf2f(v2[2]); acc.w += bf2f(v2[3]); }
        if (i3 < m) { acc.x += bf2f(v3[0]); acc.y += bf2f(v3[1]);
                      acc.z += bf2f(v3[2]); acc.w += bf2f(v3[3]); }
      }
    }
    acc.x += __shfl_xor(acc.x, 16); acc.x += __shfl_xor(acc.x, 32);
    acc.y += __shfl_xor(acc.y, 16); acc.y += __shfl_xor(acc.y, 32);
    acc.z += __shfl_xor(acc.z, 16); acc.z += __shfl_xor(acc.z, 32);
    acc.w += __shfl_xor(acc.w, 16); acc.w += __shfl_xor(acc.w, 32);
    if (g == 0) {
      const float s = 1.0f / (float)max(deg, 1);
      u16x4 o;
      o[0] = (unsigned short)f2bf(acc.x * s);
      o[1] = (unsigned short)f2bf(acc.y * s);
      o[2] = (unsigned short)f2bf(acc.z * s);
      o[3] = (unsigned short)f2bf(acc.w * s);
      *(u16x4*)(agg + (size_t)r * D + fq * 4) = o;
    }
  }
}

// ---------------- Concat-matmul via split-bf16 MFMA --------------------------
// C[100000,64] = concat(X, agg)[.,128] @ W[128,64] + b.
// Self half (s<2): precomputed bf16 hi/lo rows -> 3 MFMAs. Agg half (s>=2):
// bf16 rows (lo == 0 exactly) -> 2 MFMAs. 40 MFMAs/tile, no VALU split math.
// Layer 1 (doRelu): writes h as bf16 hi/lo pair (bit-identical to splitting
// the f32 value at layer-2 read time -> zero accuracy change).
__global__ __launch_bounds__(256) void sage_mm(
    const unsigned short* __restrict__ ah, const unsigned short* __restrict__ al,
    const unsigned short* __restrict__ aggb,
    const short* __restrict__ wh, const short* __restrict__ wl,
    const float* __restrict__ b, float* __restrict__ out,
    unsigned short* __restrict__ hh, unsigned short* __restrict__ hl,
    int doRelu) {
  const int lane = threadIdx.x & 63;
  const int m = lane & 15;
  const int q = lane >> 4;
  const int gwave = (blockIdx.x * blockDim.x + threadIdx.x) >> 6;
  const int nwaves = (gridDim.x * blockDim.x) >> 6;
  const int nTiles = N_NODES / 16;  // 6250

  for (int tile = gwave; tile < nTiles; tile += nwaves) {
    const int r0 = tile * 16;
    f32x4 acc[4];
#pragma unroll
    for (int t = 0; t < 4; ++t) {
      const float bv = b[t * 16 + m];
      acc[t][0] = bv; acc[t][1] = bv; acc[t][2] = bv; acc[t][3] = bv;
    }

#pragma unroll
    for (int s = 0; s < 4; ++s) {
      const int kb = (s & 1) * 32 + q * 8;  // offset within the 64-wide row
      const size_t ai = (size_t)(r0 + m) * D + kb;
      bf16x8 Ah, Al;
      if (s < 2) {
        Ah = *(const bf16x8*)(ah + ai);
        Al = *(const bf16x8*)(al + ai);
      } else {
        Ah = *(const bf16x8*)(aggb + ai);
      }
#pragma unroll
      for (int t = 0; t < 4; ++t) {
        const int bi = ((t * 4 + s) * 64 + lane) * 8;
        const bf16x8 Bh = *(const bf16x8*)(wh + bi);
        const bf16x8 Bl = *(const bf16x8*)(wl + bi);
        acc[t] = __builtin_amdgcn_mfma_f32_16x16x32_bf16(Ah, Bh, acc[t], 0, 0, 0);
        acc[t] = __builtin_amdgcn_mfma_f32_16x16x32_bf16(Ah, Bl, acc[t], 0, 0, 0);
        if (s < 2)
          acc[t] = __builtin_amdgcn_mfma_f32_16x16x32_bf16(Al, Bh, acc[t], 0, 0, 0);
      }
    }

    // C layout: col = t*16 + m, row = q*4 + rg
#pragma unroll
    for (int t = 0; t < 4; ++t) {
#pragma unroll
      for (int rg = 0; rg < 4; ++rg) {
        float v = acc[t][rg];
        const size_t oi = (size_t)(r0 + q * 4 + rg) * D + t * 16 + m;
        if (doRelu) {
          v = fmaxf(v, 0.0f);
          const short hv = f2bf(v);
          hh[oi] = (unsigned short)hv;
          hl[oi] = (unsigned short)f2bf(v - bf2f(hv));
        } else {
          out[oi] = v;
        }
      }
    }
  }
}

extern "C" void kernel_launch(void* const* d_in, const int* in_sizes, int n_in,
                              void* d_out, int out_size, void* d_ws, size_t ws_size,
                              hipStream_t stream) {
  const float* x  = (const float*)d_in[0];
  const int*   ei = (const int*)d_in[1];
  const float* W1 = (const float*)d_in[2];
  const float* b1 = (const float*)d_in[3];
  const float* W2 = (const float*)d_in[4];
  const float* b2 = (const float*)d_in[5];
  float* out = (float*)d_out;

  const int* row = ei;            // edge_index[0]
  const int* col = ei + N_EDGES;  // edge_index[1]

  // ws layout:
  //   ends[N] | sortedCol[E] | bucket meta | w1h|w1l|w2h|w2l (4x16KB)
  //   | xh | xl | hh | hl (4 x N*64 bf16 = 51.2MB)
  //   | union{ pairBuf[E u64] (9.6MB), aggbf[N*64 bf16] (12.8MB) }
  char* ws = (char*)d_ws;
  int* endsArr = (int*)ws;
  size_t off = ((size_t)N_NODES * sizeof(int) + 4095) & ~(size_t)4095;
  int* sortedCol = (int*)(ws + off);
  off += ((size_t)N_EDGES * sizeof(int) + 4095) & ~(size_t)4095;
  int* bucketCount = (int*)(ws + off);
  int* bucketStart = bucketCount + 512;
  int* cursor = bucketStart + 512;
  off += 8192;
  short* w1h = (short*)(ws + off); off += 8192 * sizeof(short);
  short* w1l = (short*)(ws + off); off += 8192 * sizeof(short);
  short* w2h = (short*)(ws + off); off += 8192 * sizeof(short);
  short* w2l = (short*)(ws + off); off += 8192 * sizeof(short);
  unsigned short* xh = (unsigned short*)(ws + off);
  off += (size_t)N_NODES * D * sizeof(unsigned short);
  unsigned short* xl = (unsigned short*)(ws + off);
  off += (size_t)N_NODES * D * sizeof(unsigned short);
  unsigned short* hh = (unsigned short*)(ws + off);
  off += (size_t)N_NODES * D * sizeof(unsigned short);
  unsigned short* hl = (unsigned short*)(ws + off);
  off += (size_t)N_NODES * D * sizeof(unsigned short);
  off = (off + 4095) & ~(size_t)4095;
  unsigned long long* pairBuf = (unsigned long long*)(ws + off);
  unsigned short* aggbf = (unsigned short*)(ws + off);  // union: pairBuf dead
                                                        // before first sage_agg

  hipMemsetAsync(bucketCount, 0, NB * sizeof(int), stream);

  // ---- Prep: W1/W2 swizzle + x hi/lo split (one kernel) ----
  prep<<<64 + (N_NODES * D / 8 + 255) / 256, 256, 0, stream>>>(
      x, xh, xl, W1, w1h, w1l, W2, w2h, w2l);

  // ---- CSR build: bucketed two-phase partition ----
  p1_count<<<P1_BLOCKS, 256, 0, stream>>>(row, bucketCount);
  p1_scan<<<1, 512, 0, stream>>>(bucketCount, bucketStart, cursor);
  p1_scatter<<<P1_BLOCKS, 512, 0, stream>>>(row, col, cursor, pairBuf);
  p2_csr<<<NB, 256, 0, stream>>>(pairBuf, bucketStart, endsArr, sortedCol);

  // ---- Layer 1: h = relu(concat(x, mean(x)) @ W1 + b1) -> hh/hl (bf16) ----
  sage_agg<<<2048, 256, 0, stream>>>(xh, endsArr, sortedCol, aggbf, N_NODES);
  sage_mm<<<1563, 256, 0, stream>>>(xh, xl, aggbf, w1h, w1l, b1, out, hh, hl, 1);

  // ---- Layer 2: out = concat(h, mean(h)) @ W2 + b2 ----
  sage_agg<<<2048, 256, 0, stream>>>(hh, endsArr, sortedCol, aggbf, N_NODES);
  sage_mm<<<1563, 256, 0, stream>>>(hh, hl, aggbf, w2h, w2l, b2, out, hh, hl, 0);
}

// Round 4
// 213.937 us; speedup vs baseline: 1.2444x; 1.0952x over previous
//
#include <hip/hip_runtime.h>

#define N_NODES 100000
#define N_EDGES 1200000
#define D 64

#define BSHIFT 8
#define NB ((N_NODES + 255) >> BSHIFT)          // 391 buckets of 256 nodes
#define EPB 2048                                 // edges per partition block
#define P1_BLOCKS ((N_EDGES + EPB - 1) / EPB)    // 586
#define P2_CAP 4096                              // per-bucket edge capacity

#define XSPLIT_BLOCKS (N_NODES * D / 8 / 256)    // 3125 (exact)
#define PREP_BLOCKS (XSPLIT_BLOCKS + 64)         // + 32 W1 + 32 W2
#define PC_BLOCKS (PREP_BLOCKS + P1_BLOCKS)      // + 586 count blocks

typedef short bf16x8 __attribute__((ext_vector_type(8)));
typedef float f32x4 __attribute__((ext_vector_type(4)));
typedef unsigned short u16x4 __attribute__((ext_vector_type(4)));
typedef unsigned short u16x8 __attribute__((ext_vector_type(8)));

__device__ __forceinline__ short f2bf(float x) {
  unsigned u = __float_as_uint(x);
  unsigned r = (u + 0x7FFFu + ((u >> 16) & 1u)) >> 16;  // RNE
  return (short)r;
}
__device__ __forceinline__ float bf2f(short b) {
  return __uint_as_float(((unsigned)(unsigned short)b) << 16);
}

// ---------------- Prep + p1_count fused (block-role partition) ---------------
// blocks [0, 3125):       x f32 -> xh bf16 (gather/self table)
// blocks [3125, 3157):    W1 swizzle -> w1h/w1l
// blocks [3157, 3189):    W2 swizzle -> w2h/w2l
// blocks [3189, 3775):    per-bucket edge histogram (LDS hist + global merge)
// W fragment layout: for n-tile t, k-step s, lane l:
// B[k = s*32 + (l>>4)*8 + j][n = t*16 + (l&15)], stored ((t*4+s)*64+l)*8+j.
__device__ __forceinline__ void w_swz(const float* __restrict__ W,
                                      short* __restrict__ wh,
                                      short* __restrict__ wl, int blk) {
  int i = blk * 256 + threadIdx.x;   // 0..8191
  int j = i & 7;
  int l = (i >> 3) & 63;
  int s = (i >> 9) & 3;
  int t = i >> 11;
  int k = s * 32 + ((l >> 4) * 8) + j;
  int n = t * 16 + (l & 15);
  float v = W[k * 64 + n];
  short hb = f2bf(v);
  wh[i] = hb;
  wl[i] = f2bf(v - bf2f(hb));
}

__global__ __launch_bounds__(256) void prep_count(
    const float* __restrict__ x, unsigned short* __restrict__ xh,
    const float* __restrict__ W1, short* __restrict__ w1h, short* __restrict__ w1l,
    const float* __restrict__ W2, short* __restrict__ w2h, short* __restrict__ w2l,
    const int* __restrict__ row, int* __restrict__ bucketCount) {
  const int bid = blockIdx.x;
  const int t = threadIdx.x;
  if (bid < XSPLIT_BLOCKS) {
    int i = bid * 256 + t;                       // octet index, exact cover
    const float4 a0 = *(const float4*)(x + (size_t)i * 8);
    const float4 a1 = *(const float4*)(x + (size_t)i * 8 + 4);
    const float f[8] = {a0.x, a0.y, a0.z, a0.w, a1.x, a1.y, a1.z, a1.w};
    u16x8 vh;
#pragma unroll
    for (int j = 0; j < 8; ++j) vh[j] = (unsigned short)f2bf(f[j]);
    *(u16x8*)(xh + (size_t)i * 8) = vh;
    return;
  }
  if (bid < XSPLIT_BLOCKS + 32) { w_swz(W1, w1h, w1l, bid - XSPLIT_BLOCKS); return; }
  if (bid < PREP_BLOCKS)        { w_swz(W2, w2h, w2l, bid - XSPLIT_BLOCKS - 32); return; }
  // ---- histogram role ----
  __shared__ int h[NB];
  for (int i = t; i < NB; i += 256) h[i] = 0;
  __syncthreads();
  const int base = (bid - PREP_BLOCKS) * EPB;
#pragma unroll
  for (int i = 0; i < EPB / 256; ++i) {
    int e = base + i * 256 + t;
    if (e < N_EDGES) atomicAdd(&h[row[e] >> BSHIFT], 1);
  }
  __syncthreads();
  for (int i = t; i < NB; i += 256)
    if (h[i]) atomicAdd(&bucketCount[i], h[i]);
}

// ---------------- Phase 1b: scan bucket counts -> starts + cursors ----------
__global__ __launch_bounds__(512) void p1_scan(const int* __restrict__ bucketCount,
                                               int* __restrict__ bucketStart,
                                               int* __restrict__ cursor) {
  __shared__ int lds[512];
  const int t = threadIdx.x;
  int v = (t < NB) ? bucketCount[t] : 0;
  lds[t] = v;
  __syncthreads();
  for (int off = 1; off < 512; off <<= 1) {
    int add = (t >= off) ? lds[t - off] : 0;
    __syncthreads();
    lds[t] += add;
    __syncthreads();
  }
  if (t < NB) {
    int start = lds[t] - v;
    bucketStart[t] = start;
    cursor[t] = start;
  }
  if (t == NB - 1) bucketStart[NB] = lds[t];
}

// ---------------- Phase 1c: partition (row,col) pairs into buckets -----------
__global__ __launch_bounds__(512) void p1_scatter(
    const int* __restrict__ row, const int* __restrict__ col,
    int* __restrict__ cursor, unsigned long long* __restrict__ pairBuf) {
  __shared__ int h[NB];
  __shared__ int hexcl[NB];
  __shared__ int gbase[NB];
  __shared__ int scan_lds[512];
  __shared__ unsigned long long staged[EPB];
  const int t = threadIdx.x;
  for (int i = t; i < NB; i += 512) h[i] = 0;
  __syncthreads();
  const int base = blockIdx.x * EPB;
  const int cnt = min(EPB, N_EDGES - base);

  int myrank[EPB / 512];
  int mybkt[EPB / 512];
  unsigned long long mypair[EPB / 512];
#pragma unroll
  for (int i = 0; i < EPB / 512; ++i) {
    int e = base + i * 512 + t;
    if (e < N_EDGES) {
      unsigned r = (unsigned)row[e];
      unsigned c = (unsigned)col[e];
      int b = (int)(r >> BSHIFT);
      mybkt[i] = b;
      mypair[i] = ((unsigned long long)r << 32) | c;
      myrank[i] = atomicAdd(&h[b], 1);
    } else {
      mybkt[i] = -1;
    }
  }
  __syncthreads();
  int v = (t < NB) ? h[t] : 0;
  scan_lds[t] = v;
  __syncthreads();
  for (int off = 1; off < 512; off <<= 1) {
    int add = (t >= off) ? scan_lds[t - off] : 0;
    __syncthreads();
    scan_lds[t] += add;
    __syncthreads();
  }
  if (t < NB) {
    hexcl[t] = scan_lds[t] - v;
    gbase[t] = (h[t] > 0) ? atomicAdd(&cursor[t], h[t]) : 0;
  }
  __syncthreads();
#pragma unroll
  for (int i = 0; i < EPB / 512; ++i)
    if (mybkt[i] >= 0) staged[hexcl[mybkt[i]] + myrank[i]] = mypair[i];
  __syncthreads();
  for (int i = t; i < cnt; i += 512) {
    unsigned long long p = staged[i];
    int b = (int)(p >> (32 + BSHIFT));
    pairBuf[gbase[b] + (i - hexcl[b])] = p;
  }
}

// ---------------- Phase 2: per-bucket local CSR ------------------------------
__global__ __launch_bounds__(256) void p2_csr(
    const unsigned long long* __restrict__ pairBuf,
    const int* __restrict__ bucketStart,
    int* __restrict__ ends, int* __restrict__ sortedCol) {
  __shared__ int hist[256];
  __shared__ int sc[256];
  __shared__ unsigned short rankLDS[P2_CAP];
  const int t = threadIdx.x;
  const int b = blockIdx.x;
  const int base = bucketStart[b];
  const int cnt = min(bucketStart[b + 1] - base, P2_CAP);
  hist[t] = 0;
  __syncthreads();
  for (int i = t; i < cnt; i += 256) {
    int lr = (int)((pairBuf[base + i] >> 32) & ((1 << BSHIFT) - 1));
    rankLDS[i] = (unsigned short)atomicAdd(&hist[lr], 1);
  }
  __syncthreads();
  int v = hist[t];
  sc[t] = v;
  __syncthreads();
  for (int off = 1; off < 256; off <<= 1) {
    int add = (t >= off) ? sc[t - off] : 0;
    __syncthreads();
    sc[t] += add;
    __syncthreads();
  }
  const int node = (b << BSHIFT) + t;
  if (node < N_NODES) ends[node] = base + sc[t];
  const int excl = sc[t] - v;
  __syncthreads();
  sc[t] = excl;
  __syncthreads();
  for (int i = t; i < cnt; i += 256) {
    unsigned long long p = pairBuf[base + i];
    int lr = (int)((p >> 32) & ((1 << BSHIFT) - 1));
    sortedCol[base + sc[lr] + (int)rankLDS[i]] = (int)(unsigned)p;
  }
}

// ---------------- Fused agg + concat-matmul ----------------------------------
// One block = one 16-row output tile (6250 blocks, N_NODES = 6250*16 exactly).
// Phase A: each of 4 waves aggregates 4 rows (bf16 gathers, 4-deep MLP),
//          writes bf16 means to LDS tile [16][72] (pad -> 2-way banks = free).
// Phase B: wave w computes n-tile t=w: A self-half from xsrc (bf16 rows),
//          A agg-half from LDS, 8 MFMAs (Ah*Bh + Ah*Bl per k-step).
// Layer 1 (relu): stores h as bf16 only. Layer 2: stores f32 out.
__global__ __launch_bounds__(256) void sage_fused(
    const unsigned short* __restrict__ xsrc, const int* __restrict__ ends,
    const int* __restrict__ sortedCol,
    const short* __restrict__ wh, const short* __restrict__ wl,
    const float* __restrict__ bias, float* __restrict__ outf,
    unsigned short* __restrict__ outb, int doRelu) {
  __shared__ unsigned short aggS[16][72];
  __shared__ int ends_s[17];
  const int tid = threadIdx.x;
  const int w = tid >> 6;        // wave 0..3 = n-tile index
  const int lane = tid & 63;
  const int g = lane >> 4;       // edge slot 0..3
  const int fq = lane & 15;      // feature quad 0..15
  const int r0 = blockIdx.x * 16;

  if (tid < 17) {
    int idx = r0 - 1 + tid;
    ends_s[tid] = (idx >= 0) ? ends[idx] : 0;
  }
  __syncthreads();

  // ---- Phase A: aggregate rows w*4 .. w*4+3 ----
  for (int i = 0; i < 4; ++i) {
    const int rl = w * 4 + i;
    const int start = ends_s[rl];
    const int end = ends_s[rl + 1];
    const int deg = end - start;
    float4 acc = make_float4(0.f, 0.f, 0.f, 0.f);

    for (int base = start; base < end; base += 64) {
      const int m = min(64, end - base);
      const int cv = (lane < m) ? sortedCol[base + lane] : 0;
      for (int j = 0; j < m; j += 16) {
        const int i0 = j + 0 + g, i1 = j + 4 + g, i2 = j + 8 + g, i3 = j + 12 + g;
        const int c0 = __shfl(cv, i0 < m ? i0 : 0);
        const int c1 = __shfl(cv, i1 < m ? i1 : 0);
        const int c2 = __shfl(cv, i2 < m ? i2 : 0);
        const int c3 = __shfl(cv, i3 < m ? i3 : 0);
        u16x4 v0, v1, v2, v3;
        if (i0 < m) v0 = *(const u16x4*)(xsrc + (size_t)c0 * D + fq * 4);
        if (i1 < m) v1 = *(const u16x4*)(xsrc + (size_t)c1 * D + fq * 4);
        if (i2 < m) v2 = *(const u16x4*)(xsrc + (size_t)c2 * D + fq * 4);
        if (i3 < m) v3 = *(const u16x4*)(xsrc + (size_t)c3 * D + fq * 4);
        if (i0 < m) { acc.x += bf2f(v0[0]); acc.y += bf2f(v0[1]);
                      acc.z += bf2f(v0[2]); acc.w += bf2f(v0[3]); }
        if (i1 < m) { acc.x += bf2f(v1[0]); acc.y += bf2f(v1[1]);
                      acc.z += bf2f(v1[2]); acc.w += bf2f(v1[3]); }
        if (i2 < m) { acc.x += bf2f(v2[0]); acc.y += bf2f(v2[1]);
                      acc.z += bf2f(v2[2]); acc.w += bf2f(v2[3]); }
        if (i3 < m) { acc.x += bf2f(v3[0]); acc.y += bf2f(v3[1]);
                      acc.z += bf2f(v3[2]); acc.w += bf2f(v3[3]); }
      }
    }
    acc.x += __shfl_xor(acc.x, 16); acc.x += __shfl_xor(acc.x, 32);
    acc.y += __shfl_xor(acc.y, 16); acc.y += __shfl_xor(acc.y, 32);
    acc.z += __shfl_xor(acc.z, 16); acc.z += __shfl_xor(acc.z, 32);
    acc.w += __shfl_xor(acc.w, 16); acc.w += __shfl_xor(acc.w, 32);
    if (g == 0) {
      const float s = 1.0f / (float)max(deg, 1);
      u16x4 o;
      o[0] = (unsigned short)f2bf(acc.x * s);
      o[1] = (unsigned short)f2bf(acc.y * s);
      o[2] = (unsigned short)f2bf(acc.z * s);
      o[3] = (unsigned short)f2bf(acc.w * s);
      *(u16x4*)(&aggS[rl][fq * 4]) = o;
    }
  }
  __syncthreads();

  // ---- Phase B: MFMA, wave w owns n-tile t = w (cols w*16 .. w*16+15) ----
  const int m = lane & 15;
  const int q = lane >> 4;
  f32x4 acc;
  {
    const float bv = bias[w * 16 + m];
    acc[0] = bv; acc[1] = bv; acc[2] = bv; acc[3] = bv;
  }
#pragma unroll
  for (int s = 0; s < 4; ++s) {
    const int kb = (s & 1) * 32 + q * 8;
    bf16x8 Ah;
    if (s < 2) {
      Ah = *(const bf16x8*)(xsrc + (size_t)(r0 + m) * D + kb);
    } else {
      Ah = *(const bf16x8*)(&aggS[m][kb]);
    }
    const int bi = ((w * 4 + s) * 64 + lane) * 8;
    const bf16x8 Bh = *(const bf16x8*)(wh + bi);
    const bf16x8 Bl = *(const bf16x8*)(wl + bi);
    acc = __builtin_amdgcn_mfma_f32_16x16x32_bf16(Ah, Bh, acc, 0, 0, 0);
    acc = __builtin_amdgcn_mfma_f32_16x16x32_bf16(Ah, Bl, acc, 0, 0, 0);
  }

  // C layout: col = w*16 + m, row = q*4 + rg
#pragma unroll
  for (int rg = 0; rg < 4; ++rg) {
    float v = acc[rg];
    const size_t oi = (size_t)(r0 + q * 4 + rg) * D + w * 16 + m;
    if (doRelu) {
      v = fmaxf(v, 0.0f);
      outb[oi] = (unsigned short)f2bf(v);
    } else {
      outf[oi] = v;
    }
  }
}

extern "C" void kernel_launch(void* const* d_in, const int* in_sizes, int n_in,
                              void* d_out, int out_size, void* d_ws, size_t ws_size,
                              hipStream_t stream) {
  const float* x  = (const float*)d_in[0];
  const int*   ei = (const int*)d_in[1];
  const float* W1 = (const float*)d_in[2];
  const float* b1 = (const float*)d_in[3];
  const float* W2 = (const float*)d_in[4];
  const float* b2 = (const float*)d_in[5];
  float* out = (float*)d_out;

  const int* row = ei;            // edge_index[0]
  const int* col = ei + N_EDGES;  // edge_index[1]

  // ws layout:
  //   ends[N] | sortedCol[E] | bucket meta | w1h|w1l|w2h|w2l (4x16KB)
  //   | xh (12.8MB) | hh (12.8MB) | pairBuf[E u64] (9.6MB)
  char* ws = (char*)d_ws;
  int* endsArr = (int*)ws;
  size_t off = ((size_t)N_NODES * sizeof(int) + 4095) & ~(size_t)4095;
  int* sortedCol = (int*)(ws + off);
  off += ((size_t)N_EDGES * sizeof(int) + 4095) & ~(size_t)4095;
  int* bucketCount = (int*)(ws + off);
  int* bucketStart = bucketCount + 512;
  int* cursor = bucketStart + 512;
  off += 8192;
  short* w1h = (short*)(ws + off); off += 8192 * sizeof(short);
  short* w1l = (short*)(ws + off); off += 8192 * sizeof(short);
  short* w2h = (short*)(ws + off); off += 8192 * sizeof(short);
  short* w2l = (short*)(ws + off); off += 8192 * sizeof(short);
  unsigned short* xh = (unsigned short*)(ws + off);
  off += (size_t)N_NODES * D * sizeof(unsigned short);
  unsigned short* hh = (unsigned short*)(ws + off);
  off += (size_t)N_NODES * D * sizeof(unsigned short);
  off = (off + 4095) & ~(size_t)4095;
  unsigned long long* pairBuf = (unsigned long long*)(ws + off);

  hipMemsetAsync(bucketCount, 0, NB * sizeof(int), stream);

  // ---- Prep (x->bf16, W swizzle) + bucket histogram (one kernel) ----
  prep_count<<<PC_BLOCKS, 256, 0, stream>>>(x, xh, W1, w1h, w1l, W2, w2h, w2l,
                                            row, bucketCount);

  // ---- CSR build ----
  p1_scan<<<1, 512, 0, stream>>>(bucketCount, bucketStart, cursor);
  p1_scatter<<<P1_BLOCKS, 512, 0, stream>>>(row, col, cursor, pairBuf);
  p2_csr<<<NB, 256, 0, stream>>>(pairBuf, bucketStart, endsArr, sortedCol);

  // ---- Layer 1: h = relu(concat(x, mean(x)) @ W1 + b1) -> hh (bf16) ----
  sage_fused<<<N_NODES / 16, 256, 0, stream>>>(xh, endsArr, sortedCol,
                                               w1h, w1l, b1, out, hh, 1);

  // ---- Layer 2: out = concat(h, mean(h)) @ W2 + b2 (f32) ----
  sage_fused<<<N_NODES / 16, 256, 0, stream>>>(hh, endsArr, sortedCol,
                                               w2h, w2l, b2, out, hh, 0);
}

// Round 5
// 210.370 us; speedup vs baseline: 1.2655x; 1.0170x over previous
//
#include <hip/hip_runtime.h>

#define N_NODES 100000
#define N_EDGES 1200000
#define D 64

#define BSHIFT 8
#define NB ((N_NODES + 255) >> BSHIFT)          // 391 buckets of 256 nodes
#define EPB 2048                                 // edges per partition block
#define P1_BLOCKS ((N_EDGES + EPB - 1) / EPB)    // 586
#define P2_CAP 4096                              // per-bucket edge capacity

#define XSPLIT_BLOCKS (N_NODES * D / 8 / 256)    // 3125 (exact)
#define PREP_BLOCKS (XSPLIT_BLOCKS + 64)         // + 32 W1 + 32 W2
#define PC_BLOCKS (PREP_BLOCKS + P1_BLOCKS)      // + 586 count blocks

typedef short bf16x8 __attribute__((ext_vector_type(8)));
typedef float f32x4 __attribute__((ext_vector_type(4)));
typedef unsigned short u16x4 __attribute__((ext_vector_type(4)));
typedef unsigned short u16x8 __attribute__((ext_vector_type(8)));

__device__ __forceinline__ short f2bf(float x) {
  unsigned u = __float_as_uint(x);
  unsigned r = (u + 0x7FFFu + ((u >> 16) & 1u)) >> 16;  // RNE
  return (short)r;
}
__device__ __forceinline__ float bf2f(short b) {
  return __uint_as_float(((unsigned)(unsigned short)b) << 16);
}

// ---------------- Prep + p1_count fused (block-role partition) ---------------
// blocks [0, 3125):       x f32 -> xh bf16 (gather/self table)
// blocks [3125, 3157):    W1 swizzle -> w1h/w1l
// blocks [3157, 3189):    W2 swizzle -> w2h/w2l
// blocks [3189, 3775):    per-bucket edge histogram (LDS hist + global merge)
// W fragment layout: for n-tile t, k-step s, lane l:
// B[k = s*32 + (l>>4)*8 + j][n = t*16 + (l&15)], stored ((t*4+s)*64+l)*8+j.
__device__ __forceinline__ void w_swz(const float* __restrict__ W,
                                      short* __restrict__ wh,
                                      short* __restrict__ wl, int blk) {
  int i = blk * 256 + threadIdx.x;   // 0..8191
  int j = i & 7;
  int l = (i >> 3) & 63;
  int s = (i >> 9) & 3;
  int t = i >> 11;
  int k = s * 32 + ((l >> 4) * 8) + j;
  int n = t * 16 + (l & 15);
  float v = W[k * 64 + n];
  short hb = f2bf(v);
  wh[i] = hb;
  wl[i] = f2bf(v - bf2f(hb));
}

__global__ __launch_bounds__(256) void prep_count(
    const float* __restrict__ x, unsigned short* __restrict__ xh,
    const float* __restrict__ W1, short* __restrict__ w1h, short* __restrict__ w1l,
    const float* __restrict__ W2, short* __restrict__ w2h, short* __restrict__ w2l,
    const int* __restrict__ row, int* __restrict__ bucketCount) {
  const int bid = blockIdx.x;
  const int t = threadIdx.x;
  if (bid < XSPLIT_BLOCKS) {
    int i = bid * 256 + t;                       // octet index, exact cover
    const float4 a0 = *(const float4*)(x + (size_t)i * 8);
    const float4 a1 = *(const float4*)(x + (size_t)i * 8 + 4);
    const float f[8] = {a0.x, a0.y, a0.z, a0.w, a1.x, a1.y, a1.z, a1.w};
    u16x8 vh;
#pragma unroll
    for (int j = 0; j < 8; ++j) vh[j] = (unsigned short)f2bf(f[j]);
    *(u16x8*)(xh + (size_t)i * 8) = vh;
    return;
  }
  if (bid < XSPLIT_BLOCKS + 32) { w_swz(W1, w1h, w1l, bid - XSPLIT_BLOCKS); return; }
  if (bid < PREP_BLOCKS)        { w_swz(W2, w2h, w2l, bid - XSPLIT_BLOCKS - 32); return; }
  // ---- histogram role ----
  __shared__ int h[NB];
  for (int i = t; i < NB; i += 256) h[i] = 0;
  __syncthreads();
  const int base = (bid - PREP_BLOCKS) * EPB;
#pragma unroll
  for (int i = 0; i < EPB / 256; ++i) {
    int e = base + i * 256 + t;
    if (e < N_EDGES) atomicAdd(&h[row[e] >> BSHIFT], 1);
  }
  __syncthreads();
  for (int i = t; i < NB; i += 256)
    if (h[i]) atomicAdd(&bucketCount[i], h[i]);
}

// ---------------- Phase 1b: scan bucket counts -> starts + cursors ----------
__global__ __launch_bounds__(512) void p1_scan(const int* __restrict__ bucketCount,
                                               int* __restrict__ bucketStart,
                                               int* __restrict__ cursor) {
  __shared__ int lds[512];
  const int t = threadIdx.x;
  int v = (t < NB) ? bucketCount[t] : 0;
  lds[t] = v;
  __syncthreads();
  for (int off = 1; off < 512; off <<= 1) {
    int add = (t >= off) ? lds[t - off] : 0;
    __syncthreads();
    lds[t] += add;
    __syncthreads();
  }
  if (t < NB) {
    int start = lds[t] - v;
    bucketStart[t] = start;
    cursor[t] = start;
  }
  if (t == NB - 1) bucketStart[NB] = lds[t];
}

// ---------------- Phase 1c: partition (row,col) pairs into buckets -----------
__global__ __launch_bounds__(512) void p1_scatter(
    const int* __restrict__ row, const int* __restrict__ col,
    int* __restrict__ cursor, unsigned long long* __restrict__ pairBuf) {
  __shared__ int h[NB];
  __shared__ int hexcl[NB];
  __shared__ int gbase[NB];
  __shared__ int scan_lds[512];
  __shared__ unsigned long long staged[EPB];
  const int t = threadIdx.x;
  for (int i = t; i < NB; i += 512) h[i] = 0;
  __syncthreads();
  const int base = blockIdx.x * EPB;
  const int cnt = min(EPB, N_EDGES - base);

  int myrank[EPB / 512];
  int mybkt[EPB / 512];
  unsigned long long mypair[EPB / 512];
#pragma unroll
  for (int i = 0; i < EPB / 512; ++i) {
    int e = base + i * 512 + t;
    if (e < N_EDGES) {
      unsigned r = (unsigned)row[e];
      unsigned c = (unsigned)col[e];
      int b = (int)(r >> BSHIFT);
      mybkt[i] = b;
      mypair[i] = ((unsigned long long)r << 32) | c;
      myrank[i] = atomicAdd(&h[b], 1);
    } else {
      mybkt[i] = -1;
    }
  }
  __syncthreads();
  int v = (t < NB) ? h[t] : 0;
  scan_lds[t] = v;
  __syncthreads();
  for (int off = 1; off < 512; off <<= 1) {
    int add = (t >= off) ? scan_lds[t - off] : 0;
    __syncthreads();
    scan_lds[t] += add;
    __syncthreads();
  }
  if (t < NB) {
    hexcl[t] = scan_lds[t] - v;
    gbase[t] = (h[t] > 0) ? atomicAdd(&cursor[t], h[t]) : 0;
  }
  __syncthreads();
#pragma unroll
  for (int i = 0; i < EPB / 512; ++i)
    if (mybkt[i] >= 0) staged[hexcl[mybkt[i]] + myrank[i]] = mypair[i];
  __syncthreads();
  for (int i = t; i < cnt; i += 512) {
    unsigned long long p = staged[i];
    int b = (int)(p >> (32 + BSHIFT));
    pairBuf[gbase[b] + (i - hexcl[b])] = p;
  }
}

// ---------------- Phase 2: per-bucket local CSR ------------------------------
__global__ __launch_bounds__(256) void p2_csr(
    const unsigned long long* __restrict__ pairBuf,
    const int* __restrict__ bucketStart,
    int* __restrict__ ends, int* __restrict__ sortedCol) {
  __shared__ int hist[256];
  __shared__ int sc[256];
  __shared__ unsigned short rankLDS[P2_CAP];
  const int t = threadIdx.x;
  const int b = blockIdx.x;
  const int base = bucketStart[b];
  const int cnt = min(bucketStart[b + 1] - base, P2_CAP);
  hist[t] = 0;
  __syncthreads();
  for (int i = t; i < cnt; i += 256) {
    int lr = (int)((pairBuf[base + i] >> 32) & ((1 << BSHIFT) - 1));
    rankLDS[i] = (unsigned short)atomicAdd(&hist[lr], 1);
  }
  __syncthreads();
  int v = hist[t];
  sc[t] = v;
  __syncthreads();
  for (int off = 1; off < 256; off <<= 1) {
    int add = (t >= off) ? sc[t - off] : 0;
    __syncthreads();
    sc[t] += add;
    __syncthreads();
  }
  const int node = (b << BSHIFT) + t;
  if (node < N_NODES) ends[node] = base + sc[t];
  const int excl = sc[t] - v;
  __syncthreads();
  sc[t] = excl;
  __syncthreads();
  for (int i = t; i < cnt; i += 256) {
    unsigned long long p = pairBuf[base + i];
    int lr = (int)((p >> 32) & ((1 << BSHIFT) - 1));
    sortedCol[base + sc[lr] + (int)rankLDS[i]] = (int)(unsigned)p;
  }
}

// ---------------- Fused agg + concat-matmul ----------------------------------
// One block = one 16-row output tile (6250 blocks, N_NODES = 6250*16 exactly).
// Phase A: each 16-lane group owns ONE row; lane fq accumulates features
//   fq*4..fq*4+3 across the row's edges (8 gathers in flight, no cross-lane
//   ops, no shuffles). Mean -> bf16 -> LDS tile [16][72].
// Phase B: wave w computes n-tile t=w; self-half A fragments prefetched
//   before Phase A; agg-half from LDS; 8 MFMAs (Ah*Bh + Ah*Bl per k-step).
// Layer 1 (relu): stores h as bf16 only. Layer 2: stores f32 out.
__global__ __launch_bounds__(256) void sage_fused(
    const unsigned short* __restrict__ xsrc, const int* __restrict__ ends,
    const int* __restrict__ sortedCol,
    const short* __restrict__ wh, const short* __restrict__ wl,
    const float* __restrict__ bias, float* __restrict__ outf,
    unsigned short* __restrict__ outb, int doRelu) {
  __shared__ unsigned short aggS[16][72];
  __shared__ int ends_s[17];
  const int tid = threadIdx.x;
  const int w = tid >> 6;        // wave 0..3 = n-tile index
  const int lane = tid & 63;
  const int g = lane >> 4;       // group 0..3 (Phase A row slot / Phase B q)
  const int fq = lane & 15;      // feature quad (Phase A) / out column (Phase B)
  const int r0 = blockIdx.x * 16;

  if (tid < 17) {
    int idx = r0 - 1 + tid;
    ends_s[tid] = (idx >= 0) ? ends[idx] : 0;
  }
  // Prefetch Phase-B self-row fragments + bias (latency hides under Phase A).
  const float bv = bias[w * 16 + fq];
  const bf16x8 self0 = *(const bf16x8*)(xsrc + (size_t)(r0 + fq) * D + g * 8);
  const bf16x8 self1 = *(const bf16x8*)(xsrc + (size_t)(r0 + fq) * D + 32 + g * 8);
  __syncthreads();

  // ---- Phase A: group (w*4+g) aggregates its row, 8-deep gather pipeline ----
  {
    const int rl = w * 4 + g;
    const int start = ends_s[rl];
    const int end = ends_s[rl + 1];
    const int deg = end - start;
    float4 acc = make_float4(0.f, 0.f, 0.f, 0.f);
    for (int e = start; e < end; e += 8) {
      int cc[8];
      u16x4 vv[8];
#pragma unroll
      for (int u = 0; u < 8; ++u)
        cc[u] = sortedCol[min(e + u, end - 1)];   // clamped: always valid
#pragma unroll
      for (int u = 0; u < 8; ++u)
        vv[u] = *(const u16x4*)(xsrc + (size_t)cc[u] * D + fq * 4);
#pragma unroll
      for (int u = 0; u < 8; ++u) {
        if (e + u < end) {
          acc.x += bf2f((short)vv[u][0]);
          acc.y += bf2f((short)vv[u][1]);
          acc.z += bf2f((short)vv[u][2]);
          acc.w += bf2f((short)vv[u][3]);
        }
      }
    }
    const float s = 1.0f / (float)max(deg, 1);
    u16x4 o;
    o[0] = (unsigned short)f2bf(acc.x * s);
    o[1] = (unsigned short)f2bf(acc.y * s);
    o[2] = (unsigned short)f2bf(acc.z * s);
    o[3] = (unsigned short)f2bf(acc.w * s);
    *(u16x4*)(&aggS[rl][fq * 4]) = o;
  }
  __syncthreads();

  // ---- Phase B: MFMA, wave w owns n-tile t = w (cols w*16 .. w*16+15) ----
  f32x4 acc;
  acc[0] = bv; acc[1] = bv; acc[2] = bv; acc[3] = bv;
#pragma unroll
  for (int s = 0; s < 4; ++s) {
    bf16x8 Ah;
    if (s == 0)      Ah = self0;
    else if (s == 1) Ah = self1;
    else             Ah = *(const bf16x8*)(&aggS[fq][(s & 1) * 32 + g * 8]);
    const int bi = ((w * 4 + s) * 64 + lane) * 8;
    const bf16x8 Bh = *(const bf16x8*)(wh + bi);
    const bf16x8 Bl = *(const bf16x8*)(wl + bi);
    acc = __builtin_amdgcn_mfma_f32_16x16x32_bf16(Ah, Bh, acc, 0, 0, 0);
    acc = __builtin_amdgcn_mfma_f32_16x16x32_bf16(Ah, Bl, acc, 0, 0, 0);
  }

  // C layout: col = w*16 + fq, row = g*4 + rg
#pragma unroll
  for (int rg = 0; rg < 4; ++rg) {
    float v = acc[rg];
    const size_t oi = (size_t)(r0 + g * 4 + rg) * D + w * 16 + fq;
    if (doRelu) {
      v = fmaxf(v, 0.0f);
      outb[oi] = (unsigned short)f2bf(v);
    } else {
      outf[oi] = v;
    }
  }
}

extern "C" void kernel_launch(void* const* d_in, const int* in_sizes, int n_in,
                              void* d_out, int out_size, void* d_ws, size_t ws_size,
                              hipStream_t stream) {
  const float* x  = (const float*)d_in[0];
  const int*   ei = (const int*)d_in[1];
  const float* W1 = (const float*)d_in[2];
  const float* b1 = (const float*)d_in[3];
  const float* W2 = (const float*)d_in[4];
  const float* b2 = (const float*)d_in[5];
  float* out = (float*)d_out;

  const int* row = ei;            // edge_index[0]
  const int* col = ei + N_EDGES;  // edge_index[1]

  // ws layout:
  //   ends[N] | sortedCol[E] | bucket meta | w1h|w1l|w2h|w2l (4x16KB)
  //   | xh (12.8MB) | hh (12.8MB) | pairBuf[E u64] (9.6MB)
  char* ws = (char*)d_ws;
  int* endsArr = (int*)ws;
  size_t off = ((size_t)N_NODES * sizeof(int) + 4095) & ~(size_t)4095;
  int* sortedCol = (int*)(ws + off);
  off += ((size_t)N_EDGES * sizeof(int) + 4095) & ~(size_t)4095;
  int* bucketCount = (int*)(ws + off);
  int* bucketStart = bucketCount + 512;
  int* cursor = bucketStart + 512;
  off += 8192;
  short* w1h = (short*)(ws + off); off += 8192 * sizeof(short);
  short* w1l = (short*)(ws + off); off += 8192 * sizeof(short);
  short* w2h = (short*)(ws + off); off += 8192 * sizeof(short);
  short* w2l = (short*)(ws + off); off += 8192 * sizeof(short);
  unsigned short* xh = (unsigned short*)(ws + off);
  off += (size_t)N_NODES * D * sizeof(unsigned short);
  unsigned short* hh = (unsigned short*)(ws + off);
  off += (size_t)N_NODES * D * sizeof(unsigned short);
  off = (off + 4095) & ~(size_t)4095;
  unsigned long long* pairBuf = (unsigned long long*)(ws + off);

  hipMemsetAsync(bucketCount, 0, NB * sizeof(int), stream);

  // ---- Prep (x->bf16, W swizzle) + bucket histogram (one kernel) ----
  prep_count<<<PC_BLOCKS, 256, 0, stream>>>(x, xh, W1, w1h, w1l, W2, w2h, w2l,
                                            row, bucketCount);

  // ---- CSR build ----
  p1_scan<<<1, 512, 0, stream>>>(bucketCount, bucketStart, cursor);
  p1_scatter<<<P1_BLOCKS, 512, 0, stream>>>(row, col, cursor, pairBuf);
  p2_csr<<<NB, 256, 0, stream>>>(pairBuf, bucketStart, endsArr, sortedCol);

  // ---- Layer 1: h = relu(concat(x, mean(x)) @ W1 + b1) -> hh (bf16) ----
  sage_fused<<<N_NODES / 16, 256, 0, stream>>>(xh, endsArr, sortedCol,
                                               w1h, w1l, b1, out, hh, 1);

  // ---- Layer 2: out = concat(h, mean(h)) @ W2 + b2 (f32) ----
  sage_fused<<<N_NODES / 16, 256, 0, stream>>>(hh, endsArr, sortedCol,
                                               w2h, w2l, b2, out, hh, 0);
}